// Round 3
// baseline (117.496 us; speedup 1.0000x reference)
//
#include <hip/hip_runtime.h>

#define NB  16
#define SQn 2048
#define SKn 2048
#define DHn 64
#define KS  4   // strided key splits

typedef float    f32x4 __attribute__((ext_vector_type(4)));
typedef _Float16 f16x8 __attribute__((ext_vector_type(8)));
typedef _Float16 f16x4 __attribute__((ext_vector_type(4)));

#define MFMA __builtin_amdgcn_mfma_f32_16x16x32_f16

__device__ __forceinline__ f16x8 cvt8(f32x4 a, f32x4 b) {
    f16x8 h;
    h[0] = (_Float16)a[0]; h[1] = (_Float16)a[1];
    h[2] = (_Float16)a[2]; h[3] = (_Float16)a[3];
    h[4] = (_Float16)b[0]; h[5] = (_Float16)b[1];
    h[6] = (_Float16)b[2]; h[7] = (_Float16)b[3];
    return h;
}

// stage 16B/lane: global -> LDS (HW writes uniform base + lane*16)
__device__ __forceinline__ void stage16(const void* g, unsigned char* base) {
    __builtin_amdgcn_global_load_lds(
        (const __attribute__((address_space(1))) unsigned int*)g,
        (__attribute__((address_space(3))) unsigned int*)base,
        16, 0, 0);
}

// ---------------- prepass: K -> fp16, V -> V^T fp16 ----------------
__global__ __launch_bounds__(256)
void prep_kernel(const float* __restrict__ Kg, const float* __restrict__ Vg,
                 _Float16* __restrict__ Kh, _Float16* __restrict__ VTh)
{
    const int tid = threadIdx.x;
    const int kt  = blockIdx.x;   // 0..31
    const int b   = blockIdx.y;   // 0..15
    const size_t tbase = ((size_t)b * SKn + (size_t)kt * 64) * DHn;

    { // K convert (straight copy)
        const float* s = Kg + tbase + tid * 16;
        f32x4 a0 = *(const f32x4*)(s);
        f32x4 a1 = *(const f32x4*)(s + 4);
        f32x4 a2 = *(const f32x4*)(s + 8);
        f32x4 a3 = *(const f32x4*)(s + 12);
        _Float16* d = Kh + tbase + tid * 16;
        *(f16x8*)d       = cvt8(a0, a1);
        *(f16x8*)(d + 8) = cvt8(a2, a3);
    }
    __shared__ float vt[64][68];
    {
        const int row = tid >> 2, cb = (tid & 3) * 16;
        const float* s = Vg + tbase + row * DHn + cb;
#pragma unroll
        for (int i = 0; i < 4; ++i)
            *(f32x4*)&vt[row][cb + 4 * i] = *(const f32x4*)(s + 4 * i);
    }
    __syncthreads();
    {
        const int d0 = tid >> 2, kc = (tid & 3) * 16;
        f16x8 o0, o1;
#pragma unroll
        for (int j = 0; j < 8; ++j) {
            o0[j] = (_Float16)vt[kc + j][d0];
            o1[j] = (_Float16)vt[kc + 8 + j][d0];
        }
        _Float16* d = VTh + ((size_t)b * DHn + d0) * SKn + (size_t)kt * 64 + kc;
        *(f16x8*)d       = o0;
        *(f16x8*)(d + 8) = o1;
    }
}

// ---------------- main: flash attention with strided key-splits ----------------
// Block: 4 waves, 64 queries. Split ks owns key tiles {ks, ks+4, ks+8,...}.
// Per round: waves 0,1 (kpar=0) take list entry 2r, waves 2,3 entry 2r+1.
// Writes UNNORMALIZED O-partials + l to ws (max-free softmax => merge is a sum).
__global__ __launch_bounds__(256)
void attn_split(const float* __restrict__ Qg, const _Float16* __restrict__ Kh,
                const _Float16* __restrict__ VTh, const int* __restrict__ VL,
                float* __restrict__ Opart, float* __restrict__ lpart)
{
    const int tid   = threadIdx.x;
    const int wave  = tid >> 6;
    const int lane  = tid & 63;
    const int l15   = lane & 15;
    const int q4    = lane >> 4;
    const int qhalf = wave & 1;
    const int kpar  = wave >> 1;

    const int b  = blockIdx.x & 15;
    const int qb = (blockIdx.x >> 4) & 31;
    const int ks = blockIdx.x >> 9;       // 0..3

    const int vl     = VL[b];
    const int ntiles = (vl + 63) >> 6;
    if (ntiles <= ks) return;             // block-uniform exit; merge skips this split
    const int nrounds = ((ntiles - ks - 1) >> 3) + 1;

    __shared__ __align__(16) unsigned char smem[49152];
    unsigned char* Kt0 = smem;
    unsigned char* Kt1 = smem + 8192;
    unsigned char* Vt0 = smem + 16384;
    unsigned char* Vt1 = smem + 24576;
    unsigned char* Pb  = smem + 32768 + wave * 4096;
    float* mergeO = (float*)smem;            // reuses K region after loop
    float* mergeL = (float*)(smem + 32768);  // reuses P region after loop

    const float SCALE = 0.18033688011112042f; // log2(e)/sqrt(64)
    const int qbase = qb * 64 + qhalf * 32;

    f16x8 qf[2][2];
#pragma unroll
    for (int g = 0; g < 2; ++g) {
        const float* qrow = Qg + ((size_t)b * SQn + qbase + g * 16 + l15) * DHn + q4 * 8;
#pragma unroll
        for (int c = 0; c < 2; ++c) {
            f32x4 a  = *(const f32x4*)(qrow + c * 32);
            f32x4 a2 = *(const f32x4*)(qrow + c * 32 + 4);
            a *= SCALE; a2 *= SCALE;
            qf[g][c] = cvt8(a, a2);
        }
    }

    f32x4 O[2][4];
#pragma unroll
    for (int g = 0; g < 2; ++g)
#pragma unroll
        for (int t = 0; t < 4; ++t) O[g][t] = (f32x4){0.f, 0.f, 0.f, 0.f};
    float lacc[2] = {0.f, 0.f};

    const _Float16* KhB = Kh + (size_t)b * SKn * DHn;
    const _Float16* VTB = VTh + (size_t)b * DHn * SKn;

    const int slot0 = tid, slot1 = 256 + tid;
    const int row0 = slot0 >> 3, gl0 = (slot0 & 7) ^ (row0 & 7);
    const int row1 = slot1 >> 3, gl1 = (slot1 & 7) ^ (row1 & 7);
    const int lbase0 = (wave * 64) * 16;
    const int lbase1 = (256 + wave * 64) * 16;

    for (int r = 0; r < nrounds; ++r) {
        const int tileA = ks + 8 * r;         // always < ntiles
        const int tileB = tileA + 4;          // may be >= ntiles (staged anyway, <=31)
        {
            const int ka = tileA * 64, kb = tileB * 64;
            stage16(KhB + (size_t)(ka + row0) * DHn + gl0 * 8, Kt0 + lbase0);
            stage16(KhB + (size_t)(ka + row1) * DHn + gl1 * 8, Kt0 + lbase1);
            stage16(KhB + (size_t)(kb + row0) * DHn + gl0 * 8, Kt1 + lbase0);
            stage16(KhB + (size_t)(kb + row1) * DHn + gl1 * 8, Kt1 + lbase1);
            stage16(VTB + (size_t)row0 * SKn + ka + gl0 * 8, Vt0 + lbase0);
            stage16(VTB + (size_t)row1 * SKn + ka + gl1 * 8, Vt0 + lbase1);
            stage16(VTB + (size_t)row0 * SKn + kb + gl0 * 8, Vt1 + lbase0);
            stage16(VTB + (size_t)row1 * SKn + kb + gl1 * 8, Vt1 + lbase1);
        }
        __syncthreads();

        const int kt = kpar ? tileB : tileA;
        if (kt < ntiles) {
            const unsigned char* Kb = kpar ? Kt1 : Kt0;
            const unsigned char* Vb = kpar ? Vt1 : Vt0;
            const int sw = l15 & 7;

            // S^T = K Q^T : C layout row=key=16t+4q4+reg, col=q=l15
            f32x4 st[2][4];
#pragma unroll
            for (int g = 0; g < 2; ++g)
#pragma unroll
                for (int t = 0; t < 4; ++t) st[g][t] = (f32x4){0.f, 0.f, 0.f, 0.f};
#pragma unroll
            for (int t = 0; t < 4; ++t) {
                const int row = 16 * t + l15;
#pragma unroll
                for (int c = 0; c < 2; ++c) {
                    f16x8 kf = *(const f16x8*)(Kb + row * 128 + ((((c << 2) | q4) ^ sw) * 16));
                    st[0][t] = MFMA(kf, qf[0][c], st[0][t], 0, 0, 0);
                    st[1][t] = MFMA(kf, qf[1][c], st[1][t], 0, 0, 0);
                }
            }

            // p = exp2(s'), mask last tile, accumulate l, pack -> P buffer
            const bool lastt = (kt == ntiles - 1) && (vl & 63);
#pragma unroll
            for (int g = 0; g < 2; ++g) {
                unsigned char* pdst = Pb + (g * 16 + l15) * 128 + (q4 & 1) * 8;
#pragma unroll
                for (int t = 0; t < 4; ++t) {
                    float p0 = __builtin_amdgcn_exp2f(st[g][t][0]);
                    float p1 = __builtin_amdgcn_exp2f(st[g][t][1]);
                    float p2 = __builtin_amdgcn_exp2f(st[g][t][2]);
                    float p3 = __builtin_amdgcn_exp2f(st[g][t][3]);
                    if (lastt) {
                        const int kb0 = kt * 64 + 16 * t + 4 * q4;
                        p0 = (kb0 + 0 < vl) ? p0 : 0.f;
                        p1 = (kb0 + 1 < vl) ? p1 : 0.f;
                        p2 = (kb0 + 2 < vl) ? p2 : 0.f;
                        p3 = (kb0 + 3 < vl) ? p3 : 0.f;
                    }
                    lacc[g] += (p0 + p1) + (p2 + p3);
                    f16x4 w;
                    w[0] = (_Float16)p0; w[1] = (_Float16)p1;
                    w[2] = (_Float16)p2; w[3] = (_Float16)p3;
                    *(f16x4*)(pdst + (((2 * t + (q4 >> 1)) ^ sw) * 16)) = w;
                }
            }
            asm volatile("" ::: "memory"); // same-wave DS in-order

            f16x8 pf[2][2];
#pragma unroll
            for (int g = 0; g < 2; ++g) {
                const unsigned char* psrc = Pb + (g * 16 + l15) * 128;
                pf[g][0] = *(const f16x8*)(psrc + ((q4 ^ sw) * 16));
                pf[g][1] = *(const f16x8*)(psrc + (((4 | q4) ^ sw) * 16));
            }

            // O^T += V^T P^T : C row=d=16t2+4q4+reg, col=q=l15
#pragma unroll
            for (int t2 = 0; t2 < 4; ++t2) {
                const int row = 16 * t2 + l15;
#pragma unroll
                for (int c2 = 0; c2 < 2; ++c2) {
                    f16x8 vf = *(const f16x8*)(Vb + row * 128 + ((((c2 << 2) | q4) ^ sw) * 16));
                    O[0][t2] = MFMA(vf, pf[0][c2], O[0][t2], 0, 0, 0);
                    O[1][t2] = MFMA(vf, pf[1][c2], O[1][t2], 0, 0, 0);
                }
            }
        }
        __syncthreads();
    }

    // merge kpar halves in-block; write UNNORMALIZED partials + l
    if (kpar == 1) {
#pragma unroll
        for (int g = 0; g < 2; ++g) {
            const int x = g * 16 + l15;
#pragma unroll
            for (int t2 = 0; t2 < 4; ++t2) {
                const int gd = (4 * t2 + q4) ^ l15;
                *(f32x4*)((unsigned char*)mergeO + (qhalf * 32 + x) * 256 + gd * 16) = O[g][t2];
            }
            float lt = lacc[g];
            lt += __shfl_xor(lt, 16);
            lt += __shfl_xor(lt, 32);
            if (q4 == 0) mergeL[qhalf * 32 + x] = lt;
        }
    }
    __syncthreads();
    if (kpar == 0) {
        const size_t rowbase = (size_t)b * SQn + qbase;
#pragma unroll
        for (int g = 0; g < 2; ++g) {
            const int x = g * 16 + l15;
            float lt = lacc[g];
            lt += __shfl_xor(lt, 16);
            lt += __shfl_xor(lt, 32);
            lt += mergeL[qhalf * 32 + x];
            if (q4 == 0) lpart[(size_t)ks * (NB * SQn) + rowbase + x] = lt;
            float* orow = Opart + ((size_t)ks * (NB * SQn) + rowbase + x) * DHn;
#pragma unroll
            for (int t2 = 0; t2 < 4; ++t2) {
                const int gd = (4 * t2 + q4) ^ l15;
                f32x4 part = *(const f32x4*)((const unsigned char*)mergeO + (qhalf * 32 + x) * 256 + gd * 16);
                *(f32x4*)(orow + 16 * t2 + 4 * q4) = O[g][t2] + part;
            }
        }
    }
}

// ---------------- merge: out = sum_s Opart / sum_s l ----------------
__global__ __launch_bounds__(256)
void merge_kernel(const float* __restrict__ Op, const float* __restrict__ lp,
                  const int* __restrict__ VL, float* __restrict__ Og)
{
    const int i   = blockIdx.x * 256 + threadIdx.x;  // over B*SQ*DH/4
    const int row = i >> 4;                          // b*2048 + q
    const int dc  = (i & 15) * 4;
    const int b   = row >> 11;
    const int ntiles = (VL[b] + 63) >> 6;
    const int nact   = ntiles < KS ? ntiles : KS;

    f32x4 acc = (f32x4){0.f, 0.f, 0.f, 0.f};
    float l = 0.f;
    for (int s = 0; s < nact; ++s) {
        acc += *(const f32x4*)(Op + ((size_t)s * (NB * SQn) + row) * DHn + dc);
        l   += lp[(size_t)s * (NB * SQn) + row];
    }
    const float inv = 1.f / l;
    f32x4 r = acc;
    r *= inv;
    *(f32x4*)(Og + (size_t)row * DHn + dc) = r;
}

// ---------------- R1 fallback (used only if ws too small) ----------------
__global__ __launch_bounds__(256, 2)
void attn_fwd(const float* __restrict__ Qg, const float* __restrict__ Kg,
              const float* __restrict__ Vg, const int* __restrict__ VL,
              float* __restrict__ Og)
{
    const int tid  = threadIdx.x;
    const int wave = tid >> 6;
    const int lane = tid & 63;
    const int l15  = lane & 15;
    const int q4   = lane >> 4;
    const int b  = blockIdx.x & 15;
    const int qb = blockIdx.x >> 4;
    __shared__ __align__(16) unsigned char smemf[8192 + 8192 + 4 * 2048];
    unsigned char* Klds  = smemf;
    unsigned char* VTlds = smemf + 8192;
    unsigned char* Plds  = smemf + 16384 + wave * 2048;
    const int vl = VL[b];
    const int ntiles = (vl + 63) >> 6;
    const float SCALE = 0.18033688011112042f;
    f16x8 qfr[2];
    {
        const float* qrow = Qg + ((size_t)b * SQn + (size_t)qb * 64 + wave * 16 + l15) * DHn;
#pragma unroll
        for (int c = 0; c < 2; ++c) {
            const float* s = qrow + c * 32 + q4 * 8;
            f32x4 a = *(const f32x4*)s;
            f32x4 b2 = *(const f32x4*)(s + 4);
            a *= SCALE; b2 *= SCALE;
            qfr[c] = cvt8(a, b2);
        }
    }
    f32x4 O[4];
#pragma unroll
    for (int t = 0; t < 4; ++t) O[t] = (f32x4){0.f, 0.f, 0.f, 0.f};
    float m_i[4] = {-3e38f, -3e38f, -3e38f, -3e38f};
    float l_i[4] = {0.f, 0.f, 0.f, 0.f};
    for (int kt = 0; kt < ntiles; ++kt) {
        const int k0 = kt * 64;
#pragma unroll
        for (int i = 0; i < 2; ++i) {
            int g8 = tid + i * 256;
            int row = g8 >> 3, g = g8 & 7;
            const float* s = Kg + ((size_t)b * SKn + k0 + row) * DHn + g * 8;
            f32x4 a = *(const f32x4*)s;
            f32x4 c4 = *(const f32x4*)(s + 4);
            *(f16x8*)(Klds + row * 128 + ((g ^ (row & 7)) * 16)) = cvt8(a, c4);
        }
        {
            int key = tid & 63, dg = tid >> 6;
            const float* s = Vg + ((size_t)b * SKn + k0 + key) * DHn + dg * 16;
            int swz = key >> 3;
            int koff = (key & 7) * 2;
#pragma unroll
            for (int i = 0; i < 4; ++i) {
                f32x4 v4 = *(const f32x4*)(s + i * 4);
#pragma unroll
                for (int j = 0; j < 4; ++j) {
                    int d = dg * 16 + i * 4 + j;
                    *(_Float16*)(VTlds + d * 128 + ((swz ^ (d & 7)) * 16) + koff) = (_Float16)v4[j];
                }
            }
        }
        __syncthreads();
        f32x4 accs[4];
#pragma unroll
        for (int t = 0; t < 4; ++t) accs[t] = (f32x4){0.f, 0.f, 0.f, 0.f};
#pragma unroll
        for (int t = 0; t < 4; ++t) {
            int row = t * 16 + l15;
#pragma unroll
            for (int c = 0; c < 2; ++c) {
                f16x8 kf = *(const f16x8*)(Klds + row * 128 + ((((c << 2) + q4) ^ (l15 & 7)) * 16));
                accs[t] = MFMA(qfr[c], kf, accs[t], 0, 0, 0);
            }
        }
        if (k0 + 64 > vl) {
#pragma unroll
            for (int t = 0; t < 4; ++t)
                if (k0 + t * 16 + l15 >= vl) accs[t] = (f32x4){-1e30f, -1e30f, -1e30f, -1e30f};
        }
        float al[4];
#pragma unroll
        for (int rr = 0; rr < 4; ++rr) {
            float v = fmaxf(fmaxf(accs[0][rr], accs[1][rr]), fmaxf(accs[2][rr], accs[3][rr]));
            v = fmaxf(v, __shfl_xor(v, 1));
            v = fmaxf(v, __shfl_xor(v, 2));
            v = fmaxf(v, __shfl_xor(v, 4));
            v = fmaxf(v, __shfl_xor(v, 8));
            float mnew = fmaxf(m_i[rr], v);
            al[rr] = __builtin_amdgcn_exp2f(m_i[rr] - mnew);
            m_i[rr] = mnew;
        }
#pragma unroll
        for (int rr = 0; rr < 4; ++rr) {
            float s0 = 0.f;
#pragma unroll
            for (int t = 0; t < 4; ++t) {
                float p = __builtin_amdgcn_exp2f(accs[t][rr] - m_i[rr]);
                accs[t][rr] = p;
                s0 += p;
            }
            s0 += __shfl_xor(s0, 1);
            s0 += __shfl_xor(s0, 2);
            s0 += __shfl_xor(s0, 4);
            s0 += __shfl_xor(s0, 8);
            l_i[rr] = l_i[rr] * al[rr] + s0;
            O[0][rr] *= al[rr]; O[1][rr] *= al[rr]; O[2][rr] *= al[rr]; O[3][rr] *= al[rr];
        }
#pragma unroll
        for (int rr = 0; rr < 4; ++rr) {
            int row = q4 * 4 + rr;
            int swz = row & 7;
#pragma unroll
            for (int t = 0; t < 4; ++t) {
                int g = t * 2 + (l15 >> 3);
                *(_Float16*)(Plds + row * 128 + ((g ^ swz) * 16) + (l15 & 7) * 2) = (_Float16)accs[t][rr];
            }
        }
        asm volatile("" ::: "memory");
        f16x8 pfr[2];
        pfr[0] = *(const f16x8*)(Plds + l15 * 128 + ((q4 ^ (l15 & 7)) * 16));
        pfr[1] = *(const f16x8*)(Plds + l15 * 128 + (((4 + q4) ^ (l15 & 7)) * 16));
#pragma unroll
        for (int t2 = 0; t2 < 4; ++t2) {
            int d = t2 * 16 + l15;
#pragma unroll
            for (int c2 = 0; c2 < 2; ++c2) {
                f16x8 vf = *(const f16x8*)(VTlds + d * 128 + ((((c2 << 2) + q4) ^ (l15 & 7)) * 16));
                O[t2] = MFMA(pfr[c2], vf, O[t2], 0, 0, 0);
            }
        }
        __syncthreads();
    }
    float inv[4];
#pragma unroll
    for (int rr = 0; rr < 4; ++rr) inv[rr] = 1.f / l_i[rr];
    float* orow = Og + ((size_t)b * SQn + (size_t)qb * 64 + wave * 16 + q4 * 4) * DHn;
#pragma unroll
    for (int rr = 0; rr < 4; ++rr)
#pragma unroll
        for (int t2 = 0; t2 < 4; ++t2)
            orow[rr * DHn + t2 * 16 + l15] = O[t2][rr] * inv[rr];
}

extern "C" void kernel_launch(void* const* d_in, const int* in_sizes, int n_in,
                              void* d_out, int out_size, void* d_ws, size_t ws_size,
                              hipStream_t stream) {
    (void)in_sizes; (void)n_in; (void)out_size;
    const float* Q = (const float*)d_in[0];
    const float* K = (const float*)d_in[1];
    const float* V = (const float*)d_in[2];
    const int*  VLp = (const int*)d_in[3];
    float* O = (float*)d_out;

    const size_t kv_elems = (size_t)NB * SKn * DHn;          // 2M
    const size_t rows     = (size_t)NB * SQn;                // 32768
    // ws layout: Kh (4MB f16) | VTh (4MB f16) | Opart (KS*rows*64 f32 = 33.5MB) | lpart (KS*rows f32)
    const size_t off_Kh = 0;
    const size_t off_VT = kv_elems * sizeof(_Float16);
    const size_t off_Op = off_VT + kv_elems * sizeof(_Float16);
    const size_t off_lp = off_Op + (size_t)KS * rows * DHn * sizeof(float);
    const size_t need   = off_lp + (size_t)KS * rows * sizeof(float);

    if (ws_size >= need) {
        _Float16* Kh  = (_Float16*)((char*)d_ws + off_Kh);
        _Float16* VTh = (_Float16*)((char*)d_ws + off_VT);
        float* Opart  = (float*)((char*)d_ws + off_Op);
        float* lpart  = (float*)((char*)d_ws + off_lp);
        hipLaunchKernelGGL(prep_kernel, dim3(SKn / 64, NB), dim3(256), 0, stream, K, V, Kh, VTh);
        hipLaunchKernelGGL(attn_split, dim3(NB * (SQn / 64) * KS), dim3(256), 0, stream,
                           Q, Kh, VTh, VLp, Opart, lpart);
        hipLaunchKernelGGL(merge_kernel, dim3((NB * SQn * DHn / 4) / 256), dim3(256), 0, stream,
                           Opart, lpart, VLp, O);
    } else {
        hipLaunchKernelGGL(attn_fwd, dim3(NB * (SQn / 64)), dim3(256), 0, stream, Q, K, V, VLp, O);
    }
}